// Round 2
// 653.344 us; speedup vs baseline: 1.0086x; 1.0086x over previous
//
#include <hip/hip_runtime.h>
#include <hip/hip_bf16.h>
#include <cstddef>
#include <cstdint>

// Problem constants
#define BATCH 4
#define INC   256
#define HID   16
#define NL    9
#define HH    192
#define WW    192
#define PIX   (HH*WW)          // 36864
#define BPIX  (BATCH*PIX)      // 147456
#define OUTC  128
#define CATC  (NL*HID*2)       // 288
#define CATK  160              // per-branch K padded 144 -> 160 (5 x 32)

// cen_t plane layout: [b][y][kc=c/32][x][c%32]  (ushorts)
#define KCSTRIDE (WW*32)       // 6144 ushorts between kc chunks
#define ROWSTRIDE (8*WW*32)    // 49152 ushorts per (b,y) row

typedef __attribute__((ext_vector_type(8))) short bf16x8;
typedef __attribute__((ext_vector_type(4))) float f32x4;
typedef unsigned short ushort_t;

__device__ inline unsigned short f2bf(float f) {
  unsigned int u = __float_as_uint(f);
  u += 0x7FFF + ((u >> 16) & 1);   // round-to-nearest-even
  return (unsigned short)(u >> 16);
}
__device__ inline float bf2f(unsigned short s) {
  return __uint_as_float(((unsigned)s) << 16);
}
__device__ inline unsigned pack2(float a, float b) {
  return (unsigned)f2bf(a) | ((unsigned)f2bf(b) << 16);
}
__device__ inline bf16x8 cvt8(float4 a, float4 b) {
  union { bf16x8 v; unsigned u[4]; } r;
  r.u[0] = pack2(a.x, a.y); r.u[1] = pack2(a.z, a.w);
  r.u[2] = pack2(b.x, b.y); r.u[3] = pack2(b.z, b.w);
  return r.v;
}

// ---------------------------------------------------------------------------
// kernelP: cen (NCHW fp32) -> cen_t hi/lo planes [b][y][kc][x][32c] bf16
// ---------------------------------------------------------------------------
__global__ __launch_bounds__(256) void kernelP(const float* __restrict__ cen,
                                               ushort_t* __restrict__ th,
                                               ushort_t* __restrict__ tl) {
  __shared__ float t[256][17];
  const int b = blockIdx.z, y = blockIdx.y, x0 = blockIdx.x * 16;
  const int tid = threadIdx.x;
#pragma unroll
  for (int k = 0; k < 16; ++k) {
    int i = tid + k * 256; int c = i >> 4, xl = i & 15;
    t[c][xl] = cen[((size_t)(b * 256 + c)) * PIX + (size_t)y * WW + x0 + xl];
  }
  __syncthreads();
  const size_t rowbase = (size_t)(b * HH + y) * ROWSTRIDE;
  const int kcq = tid >> 5;        // 0..7  (channel chunk)
  const int c32 = tid & 31;        // channel within chunk
  const size_t obase = rowbase + (size_t)kcq * KCSTRIDE + c32;
#pragma unroll
  for (int xl = 0; xl < 16; ++xl) {
    float v = t[tid][xl];
    unsigned short hi = f2bf(v);
    const size_t a = obase + (size_t)(x0 + xl) * 32;
    th[a] = hi;
    tl[a] = f2bf(v - bf2f(hi));
  }
}

// ---------------------------------------------------------------------------
// wprepA: MFMA-frag-ready bf16 hi/lo weights for the two input convs.
// ---------------------------------------------------------------------------
__global__ __launch_bounds__(256) void wprepA(
    const float* __restrict__ w0, const float* __restrict__ w1,
    ushort_t* __restrict__ wA0hi, ushort_t* __restrict__ wA0lo,
    ushort_t* __restrict__ wA1hi, ushort_t* __restrict__ wA1lo) {
  int idx = blockIdx.x * 256 + threadIdx.x;
  if (idx < 36864) {
    int j = idx & 7, l = (idx >> 3) & 63, kc = (idx >> 9) & 7, s = idx >> 12;
    int d = l & 15, c = kc * 32 + (l >> 4) * 8 + j;
    float v = w1[(size_t)(d * 256 + c) * 9 + s];
    unsigned short hi = f2bf(v);
    wA1hi[idx] = hi; wA1lo[idx] = f2bf(v - bf2f(hi));
  }
  if (idx < 4096) {
    int j = idx & 7, l = (idx >> 3) & 63, kc = idx >> 9;
    int d = l & 15, c = kc * 32 + (l >> 4) * 8 + j;
    float v = w0[d * 256 + c];
    unsigned short hi = f2bf(v);
    wA0hi[idx] = hi; wA0lo[idx] = f2bf(v - bf2f(hi));
  }
}

// ---------------------------------------------------------------------------
// wprepB: out_w (fp32, [128][288]) -> wb (bf16, [branch][128][CATK]), K-padded
// ---------------------------------------------------------------------------
__global__ __launch_bounds__(256) void wprepB(const float* __restrict__ out_w,
                                              ushort_t* __restrict__ wb) {
  int idx = blockIdx.x * 256 + threadIdx.x;
  if (idx >= 2 * OUTC * CATK) return;
  int k = idx % CATK; int rest = idx / CATK;
  int o = rest % OUTC; int br = rest / OUTC;
  float v = (k < 144) ? out_w[o * CATC + br * 144 + k] : 0.f;
  wb[idx] = f2bf(v);
}

// ---------------------------------------------------------------------------
// wprepM: w1/w2/w3 (both branches) -> A-frag bf16 layout for kernelB1m.
// ---------------------------------------------------------------------------
__global__ __launch_bounds__(256) void wprepM(
    const float* __restrict__ w1_0, const float* __restrict__ w2_0,
    const float* __restrict__ w3_0, const float* __restrict__ w1_1,
    const float* __restrict__ w2_1, const float* __restrict__ w3_1,
    ushort_t* __restrict__ wm) {
  int idx = blockIdx.x * 256 + threadIdx.x;
  if (idx >= 2 * 27 * 512) return;
  int j = idx & 7;
  int lane = (idx >> 3) & 63;
  int blk = idx >> 9;               // br*27 + mat*9 + g
  int g = blk % 9, mat = (blk / 9) % 3, br = blk / 27;
  int d = lane & 15, k = (lane >> 4) * 8 + j;
  float v = 0.f;
  if (k < 16) {
    const float* w;
    if (br == 0) w = (mat == 0) ? w1_0 : (mat == 1) ? w2_0 : w3_0;
    else         w = (mat == 0) ? w1_1 : (mat == 1) ? w2_1 : w3_1;
    v = w[(g * 16 + d) * 16 + k];
    if (g < 8) v = -v;
  }
  wm[idx] = f2bf(v);
}

// ---------------------------------------------------------------------------
// kernelA_mfma: acc1 += 3x3 conv (9 taps), acc0 += 1x1 (center), hi/lo bf16.
// Plane layout [b][y][kc][x][32c] -> every 16B/lane load is a contiguous
// 1 KB wave transaction. Output h layout: NHWC [b][pix][16] fp32.
// ---------------------------------------------------------------------------
template <bool SAFE>
__device__ inline void a_tile(const ushort_t* __restrict__ th,
                              const ushort_t* __restrict__ tl,
                              const ushort_t* __restrict__ wA0hi,
                              const ushort_t* __restrict__ wA0lo,
                              const ushort_t* __restrict__ wA1hi,
                              const ushort_t* __restrict__ wA1lo,
                              int b, int y, int px, f32x4& acc0, f32x4& acc1) {
  const int lane = threadIdx.x & 63;
  const int quad = lane >> 4;
  const bf16x8 bz = {0, 0, 0, 0, 0, 0, 0, 0};
#pragma unroll
  for (int sy = 0; sy < 3; ++sy) {
    const int yy = y + sy - 1;
    const bool yok = SAFE || ((unsigned)yy < (unsigned)HH);
#pragma unroll
    for (int sx = 0; sx < 3; ++sx) {
      const int xx = px + sx - 1;
      const bool ok = SAFE || (yok && ((unsigned)xx < (unsigned)WW));
      const int cy = SAFE ? yy : (ok ? yy : 0);
      const int cx = SAFE ? xx : (ok ? xx : 0);
      const size_t base =
          (size_t)(b * HH + cy) * ROWSTRIDE + (size_t)cx * 32 + quad * 8;
      const int s = sy * 3 + sx;
      const ushort_t* wh = wA1hi + s * 4096 + lane * 8;
      const ushort_t* wl = wA1lo + s * 4096 + lane * 8;
#pragma unroll
      for (int kc = 0; kc < 8; ++kc) {
        bf16x8 bhi = *(const bf16x8*)(th + base + kc * KCSTRIDE);
        bf16x8 blo = *(const bf16x8*)(tl + base + kc * KCSTRIDE);
        if (!SAFE && !ok) { bhi = bz; blo = bz; }
        bf16x8 ahi = *(const bf16x8*)(wh + kc * 512);
        bf16x8 alo = *(const bf16x8*)(wl + kc * 512);
        acc1 = __builtin_amdgcn_mfma_f32_16x16x32_bf16(ahi, bhi, acc1, 0, 0, 0);
        acc1 = __builtin_amdgcn_mfma_f32_16x16x32_bf16(ahi, blo, acc1, 0, 0, 0);
        acc1 = __builtin_amdgcn_mfma_f32_16x16x32_bf16(alo, bhi, acc1, 0, 0, 0);
        if (s == 4) {
          bf16x8 a0h = *(const bf16x8*)(wA0hi + kc * 512 + lane * 8);
          bf16x8 a0l = *(const bf16x8*)(wA0lo + kc * 512 + lane * 8);
          acc0 = __builtin_amdgcn_mfma_f32_16x16x32_bf16(a0h, bhi, acc0, 0, 0, 0);
          acc0 = __builtin_amdgcn_mfma_f32_16x16x32_bf16(a0h, blo, acc0, 0, 0, 0);
          acc0 = __builtin_amdgcn_mfma_f32_16x16x32_bf16(a0l, bhi, acc0, 0, 0, 0);
        }
      }
    }
  }
}

// Grid: 1-D, 2304 blocks, XCD-chunked swizzle so y-adjacent tiles share an
// XCD's L2 (the 3x y-tap re-read becomes L2 hits instead of HBM misses).
__global__ __launch_bounds__(256) void kernelA_mfma(
    const ushort_t* __restrict__ th, const ushort_t* __restrict__ tl,
    const ushort_t* __restrict__ wA0hi, const ushort_t* __restrict__ wA0lo,
    const ushort_t* __restrict__ wA1hi, const ushort_t* __restrict__ wA1lo,
    const float* __restrict__ b0, const float* __restrict__ b1,
    float* __restrict__ h0, float* __restrict__ h1) {
  // 2304 % 8 == 0 -> bijective chunked swizzle: XCD k owns lt in [k*288,(k+1)*288)
  const int lt = (blockIdx.x & 7) * (2304 / 8) + (blockIdx.x >> 3);
  const int xb = lt % 3;
  const int y  = (lt / 3) % HH;
  const int b  = lt / (3 * HH);

  const int lane = threadIdx.x & 63, wave = threadIdx.x >> 6;
  const int n = lane & 15, quad = lane >> 4;
  const int wpx0 = xb * 64 + wave * 16;
  const int px = wpx0 + n;
  f32x4 acc0 = {0.f, 0.f, 0.f, 0.f}, acc1 = {0.f, 0.f, 0.f, 0.f};

  const bool safe = (y >= 1) && (y <= HH - 2) && (wpx0 >= 1) && (wpx0 + 16 <= WW - 1);
  if (safe)
    a_tile<true>(th, tl, wA0hi, wA0lo, wA1hi, wA1lo, b, y, px, acc0, acc1);
  else
    a_tile<false>(th, tl, wA0hi, wA0lo, wA1hi, wA1lo, b, y, px, acc0, acc1);

  // NHWC store: lane holds d = quad*4 + i for pixel px.
  const size_t pb = ((size_t)b * PIX + (size_t)y * WW + px) * 16 + quad * 4;
  float4 r0, r1;
  r0.x = acc0[0] + b0[quad * 4 + 0]; r0.y = acc0[1] + b0[quad * 4 + 1];
  r0.z = acc0[2] + b0[quad * 4 + 2]; r0.w = acc0[3] + b0[quad * 4 + 3];
  r1.x = acc1[0] + b1[quad * 4 + 0]; r1.y = acc1[1] + b1[quad * 4 + 1];
  r1.z = acc1[2] + b1[quad * 4 + 2]; r1.w = acc1[3] + b1[quad * 4 + 3];
  *(float4*)(h0 + pb) = r0;
  *(float4*)(h1 + pb) = r1;
}

// ---------------------------------------------------------------------------
// kernelA_f32: fallback when ws too small for cen_t planes. NHWC output.
// ---------------------------------------------------------------------------
__global__ __launch_bounds__(256) void kernelA_f32(
    const float* __restrict__ cen, const float* __restrict__ w0,
    const float* __restrict__ b0,  const float* __restrict__ w1,
    const float* __restrict__ b1,  float* __restrict__ h0,
    float* __restrict__ h1) {
  __shared__ float lds[16 * 18 * 18];
  const int lx = threadIdx.x, ly = threadIdx.y;
  const int tid = ly * 16 + lx;
  const int x0 = blockIdx.x * 16, y0 = blockIdx.y * 16, b = blockIdx.z;

  float acc0[16], acc1[16];
#pragma unroll
  for (int d = 0; d < 16; ++d) { acc0[d] = 0.f; acc1[d] = 0.f; }

  for (int cb = 0; cb < INC; cb += 16) {
    __syncthreads();
    for (int i = tid; i < 16 * 18 * 18; i += 256) {
      int c = i / 324; int rem = i - c * 324;
      int yy = rem / 18; int xx = rem - yy * 18;
      int gy = y0 + yy - 1, gx = x0 + xx - 1;
      float v = 0.f;
      if (gy >= 0 && gy < HH && gx >= 0 && gx < WW)
        v = cen[(((size_t)b * INC + cb + c) * HH + gy) * WW + gx];
      lds[i] = v;
    }
    __syncthreads();
    for (int c = 0; c < 16; ++c) {
      float v[9];
#pragma unroll
      for (int r = 0; r < 9; ++r) {
        const int dy = r / 3, dx = r - (r / 3) * 3;
        v[r] = lds[(c * 18 + ly + dy) * 18 + lx + dx];
      }
      const int cc = cb + c;
#pragma unroll
      for (int d = 0; d < 16; ++d)
        acc0[d] = fmaf(w0[d * INC + cc], v[4], acc0[d]);
#pragma unroll
      for (int d = 0; d < 16; ++d) {
        float a = acc1[d];
#pragma unroll
        for (int r = 0; r < 9; ++r)
          a = fmaf(w1[(d * INC + cc) * 9 + r], v[r], a);
        acc1[d] = a;
      }
    }
  }
  const int y = y0 + ly, x = x0 + lx;
  const size_t base = ((size_t)b * PIX + (size_t)y * WW + x) * 16;
#pragma unroll
  for (int k = 0; k < 4; ++k) {
    float4 r0, r1;
    r0.x = acc0[4 * k + 0] + b0[4 * k + 0]; r0.y = acc0[4 * k + 1] + b0[4 * k + 1];
    r0.z = acc0[4 * k + 2] + b0[4 * k + 2]; r0.w = acc0[4 * k + 3] + b0[4 * k + 3];
    r1.x = acc1[4 * k + 0] + b1[4 * k + 0]; r1.y = acc1[4 * k + 1] + b1[4 * k + 1];
    r1.z = acc1[4 * k + 2] + b1[4 * k + 2]; r1.w = acc1[4 * k + 3] + b1[4 * k + 3];
    *(float4*)(h0 + base + 4 * k) = r0;
    *(float4*)(h1 + base + 4 * k) = r1;
  }
}

// ---------------------------------------------------------------------------
// kernelB1m: wave-cooperative attention. Wave = 16 pixels of one row.
// XCD-chunked swizzle on the block index for h-tap L2 locality.
// ---------------------------------------------------------------------------
template <int SHIFT, int BRANCH>
__global__ __launch_bounds__(256) void kernelB1m(
    const float* __restrict__ h,      // [b][pix][16] fp32
    const ushort_t* __restrict__ wm,  // [br][3][9][512] bf16 A-frags
    const float* __restrict__ scale, ushort_t* __restrict__ cat) {
  const int lane = threadIdx.x & 63;
  // 2304 blocks, chunked XCD swizzle (2304 % 8 == 0)
  const int bw = (blockIdx.x & 7) * (2304 / 8) + (blockIdx.x >> 3);
  const int gw = bw * 4 + (threadIdx.x >> 6);
  const int bpix0 = gw * 16;
  const int b = bpix0 / PIX;
  const int rem = bpix0 - b * PIX;
  const int y = rem / WW, x0 = rem - y * WW;
  const int n = lane & 15, quad = lane >> 4;
  const float sc = scale[BRANCH];
  const float* __restrict__ hb = h + (size_t)b * PIX * 16;
  const ushort_t* __restrict__ wmb = wm + (size_t)BRANCH * 27 * 512;

  constexpr int DY[9] = {-1, -1, -1, 0, 1, 1, 1, 0, 0};
  constexpr int DX[9] = {-1, 0, 1, 1, 1, 0, -1, -1, 0};

  // B-frags: lane provides B[k = quad*8+j][pixel n]; k>=16 must be zero.
  bf16x8 xf[9];
#pragma unroll
  for (int g = 0; g < 9; ++g) {
    bf16x8 v = {0, 0, 0, 0, 0, 0, 0, 0};
    const int yy = y + DY[g] * SHIFT;
    const int xx = x0 + n + DX[g] * SHIFT;
    if (quad < 2 && (unsigned)yy < (unsigned)HH && (unsigned)xx < (unsigned)WW) {
      const float4* p = (const float4*)(hb + ((size_t)yy * WW + xx) * 16 + quad * 8);
      v = cvt8(p[0], p[1]);
    }
    xf[g] = v;
  }

  const f32x4 zero4 = {0.f, 0.f, 0.f, 0.f};
  f32x4 o1[9], o3[9];
#pragma unroll
  for (int g = 0; g < 9; ++g) {
    const bf16x8 a1 = *(const bf16x8*)(wmb + (0 * 9 + g) * 512 + lane * 8);
    o1[g] = __builtin_amdgcn_mfma_f32_16x16x32_bf16(a1, xf[g], zero4, 0, 0, 0);
  }
#pragma unroll
  for (int g = 0; g < 9; ++g) {
    const bf16x8 a3 = *(const bf16x8*)(wmb + (2 * 9 + g) * 512 + lane * 8);
    o3[g] = __builtin_amdgcn_mfma_f32_16x16x32_bf16(a3, xf[g], zero4, 0, 0, 0);
  }

  ushort_t* __restrict__ crow = cat + (size_t)(bpix0 + n) * CATK;

#pragma unroll
  for (int p = 0; p < 9; ++p) {
    const bf16x8 a2 = *(const bf16x8*)(wmb + (1 * 9 + p) * 512 + lane * 8);
    const f32x4 o2p = __builtin_amdgcn_mfma_f32_16x16x32_bf16(a2, xf[p], zero4, 0, 0, 0);
    float e[9]; float m = -1e30f;
#pragma unroll
    for (int q = 0; q < 9; ++q) {
      float t = (o2p[0] * o1[q][0] + o2p[1] * o1[q][1]) +
                (o2p[2] * o1[q][2] + o2p[3] * o1[q][3]);
      t += __shfl_xor(t, 16);
      t += __shfl_xor(t, 32);
      e[q] = sc * t;
      m = fmaxf(m, e[q]);
    }
    float s = 0.f;
#pragma unroll
    for (int q = 0; q < 9; ++q) { e[q] = __expf(e[q] - m); s += e[q]; }
    const float inv = 1.0f / s;
    f32x4 ov = zero4;
#pragma unroll
    for (int q = 0; q < 9; ++q) {
      const float a = e[q] * inv;
      ov[0] = fmaf(a, o3[q][0], ov[0]);
      ov[1] = fmaf(a, o3[q][1], ov[1]);
      ov[2] = fmaf(a, o3[q][2], ov[2]);
      ov[3] = fmaf(a, o3[q][3], ov[3]);
    }
    uint2 w; w.x = pack2(ov[0], ov[1]); w.y = pack2(ov[2], ov[3]);
    *(uint2*)(crow + p * 16 + quad * 4) = w;
  }
  // zero K-pad [144,160): quads 0/1 write 8 ushorts each
  if (quad < 2)
    *(uint4*)(crow + 144 + quad * 8) = make_uint4(0, 0, 0, 0);
}

// ---------------------------------------------------------------------------
// Kernel B2 split and fused variants (final 1x1 conv as bf16 MFMA GEMM).
// ---------------------------------------------------------------------------
template <int BRANCH, bool ACCUM>
__global__ __launch_bounds__(256) void kernelB2(
    const ushort_t* __restrict__ cat, const ushort_t* __restrict__ wb,
    const float* __restrict__ out_b, float* __restrict__ out) {
  const int wave = threadIdx.x >> 6;
  const int lane = threadIdx.x & 63;
  const int tile = blockIdx.x * 4 + wave;
  const int bpix0 = tile * 16;
  const int n = lane & 15, quad = lane >> 4;

  const bf16x8* __restrict__ bp =
      (const bf16x8*)(cat + (size_t)(bpix0 + n) * CATK + quad * 8);
  const ushort_t* __restrict__ wrow0 =
      wb + ((size_t)BRANCH * OUTC + n) * CATK + quad * 8;

  f32x4 acc[8];
#pragma unroll
  for (int mt = 0; mt < 8; ++mt) acc[mt] = (f32x4){0.f, 0.f, 0.f, 0.f};

#pragma unroll
  for (int kc = 0; kc < 5; ++kc) {
    const bf16x8 bfrag = bp[kc * 4];
#pragma unroll
    for (int mt = 0; mt < 8; ++mt) {
      const bf16x8 afrag =
          *(const bf16x8*)(wrow0 + (size_t)mt * 16 * CATK + kc * 32);
      acc[mt] = __builtin_amdgcn_mfma_f32_16x16x32_bf16(afrag, bfrag, acc[mt], 0, 0, 0);
    }
  }

  const int b = bpix0 / PIX;
  const int pin = bpix0 - b * PIX + n;
#pragma unroll
  for (int mt = 0; mt < 8; ++mt) {
#pragma unroll
    for (int i = 0; i < 4; ++i) {
      const int o = mt * 16 + quad * 4 + i;
      const size_t addr = ((size_t)(b * OUTC + o)) * PIX + pin;
      float r = acc[mt][i];
      if (ACCUM) r += out[addr]; else r += out_b[o];
      out[addr] = r;
    }
  }
}

__global__ __launch_bounds__(256) void kernelB2fused(
    const ushort_t* __restrict__ cat0, const ushort_t* __restrict__ cat1,
    const ushort_t* __restrict__ wb, const float* __restrict__ out_b,
    float* __restrict__ out) {
  const int wave = threadIdx.x >> 6;
  const int lane = threadIdx.x & 63;
  const int tile = blockIdx.x * 4 + wave;
  const int bpix0 = tile * 16;
  const int n = lane & 15, quad = lane >> 4;

  f32x4 acc[8];
#pragma unroll
  for (int mt = 0; mt < 8; ++mt) acc[mt] = (f32x4){0.f, 0.f, 0.f, 0.f};

#pragma unroll
  for (int br = 0; br < 2; ++br) {
    const ushort_t* cp = br ? cat1 : cat0;
    const bf16x8* __restrict__ bp =
        (const bf16x8*)(cp + (size_t)(bpix0 + n) * CATK + quad * 8);
    const ushort_t* __restrict__ wrow0 =
        wb + ((size_t)br * OUTC + n) * CATK + quad * 8;
#pragma unroll
    for (int kc = 0; kc < 5; ++kc) {
      const bf16x8 bfrag = bp[kc * 4];
#pragma unroll
      for (int mt = 0; mt < 8; ++mt) {
        const bf16x8 afrag =
            *(const bf16x8*)(wrow0 + (size_t)mt * 16 * CATK + kc * 32);
        acc[mt] = __builtin_amdgcn_mfma_f32_16x16x32_bf16(afrag, bfrag, acc[mt], 0, 0, 0);
      }
    }
  }

  const int b = bpix0 / PIX;
  const int pin = bpix0 - b * PIX + n;
#pragma unroll
  for (int mt = 0; mt < 8; ++mt) {
#pragma unroll
    for (int i = 0; i < 4; ++i) {
      const int o = mt * 16 + quad * 4 + i;
      const size_t addr = ((size_t)(b * OUTC + o)) * PIX + pin;
      out[addr] = acc[mt][i] + out_b[o];
    }
  }
}

// ---------------------------------------------------------------------------
extern "C" void kernel_launch(void* const* d_in, const int* in_sizes, int n_in,
                              void* d_out, int out_size, void* d_ws, size_t ws_size,
                              hipStream_t stream) {
  const float* cen   = (const float*)d_in[0];
  const float* in_w0 = (const float*)d_in[1];
  const float* in_b0 = (const float*)d_in[2];
  const float* in_w1 = (const float*)d_in[3];
  const float* in_b1 = (const float*)d_in[4];
  const float* w1_0  = (const float*)d_in[5];
  const float* w2_0  = (const float*)d_in[6];
  const float* w3_0  = (const float*)d_in[7];
  const float* w1_1  = (const float*)d_in[8];
  const float* w2_1  = (const float*)d_in[9];
  const float* w3_1  = (const float*)d_in[10];
  const float* scale = (const float*)d_in[11];
  const float* out_w = (const float*)d_in[12];
  const float* out_b = (const float*)d_in[13];
  float* out = (float*)d_out;

  // ---- ws layout ----
  const size_t H_ELEMS = (size_t)BATCH * HID * PIX;        // 2359296 floats
  const size_t PLANE_E = (size_t)BPIX * 256;               // cen_t plane, ushorts
  const size_t CAT_E   = (size_t)BPIX * CATK;              // cat, ushorts

  float* h0 = (float*)d_ws;
  float* h1 = h0 + H_ELEMS;
  ushort_t* wsm = (ushort_t*)(h1 + H_ELEMS);
  ushort_t* wA0hi = wsm;                 // 4096
  ushort_t* wA0lo = wsm + 4096;          // 4096
  ushort_t* wA1hi = wsm + 8192;          // 36864
  ushort_t* wA1lo = wsm + 45056;         // 36864
  ushort_t* wb    = wsm + 81920;         // 40960
  ushort_t* wm    = wsm + 122880;        // 27648
  ushort_t* big   = wsm + 150528;

  const size_t base_bytes = 2 * H_ELEMS * 4 + 150528 * 2;
  const size_t fast_need       = base_bytes + 2 * PLANE_E * 2;   // ~170 MB
  const size_t slow_fused_need = base_bytes + 2 * CAT_E * 2;     // ~114 MB
  const bool fast  = ws_size >= fast_need;
  const bool fused = fast || ws_size >= slow_fused_need;

  ushort_t* cat0 = big;                         // fast: aliases cen_t (stream-ordered)
  ushort_t* cat1 = fused ? (big + CAT_E) : big;

  // ---- weight preps ----
  hipLaunchKernelGGL(wprepB, dim3((2 * OUTC * CATK + 255) / 256), dim3(256), 0,
                     stream, out_w, wb);
  hipLaunchKernelGGL(wprepM, dim3((2 * 27 * 512 + 255) / 256), dim3(256), 0,
                     stream, w1_0, w2_0, w3_0, w1_1, w2_1, w3_1, wm);

  // ---- input convs ----
  if (fast) {
    ushort_t* th = big;
    ushort_t* tl = big + PLANE_E;
    hipLaunchKernelGGL(wprepA, dim3(144), dim3(256), 0, stream,
                       in_w0, in_w1, wA0hi, wA0lo, wA1hi, wA1lo);
    hipLaunchKernelGGL(kernelP, dim3(WW / 16, HH, BATCH), dim3(256), 0, stream,
                       cen, th, tl);
    hipLaunchKernelGGL(kernelA_mfma, dim3(3 * HH * BATCH), dim3(256), 0, stream,
                       th, tl, wA0hi, wA0lo, wA1hi, wA1lo, in_b0, in_b1, h0, h1);
  } else {
    hipLaunchKernelGGL(kernelA_f32, dim3(WW / 16, HH / 16, BATCH), dim3(16, 16), 0,
                       stream, cen, in_w0, in_b0, in_w1, in_b1, h0, h1);
  }

  const int nb1 = (BPIX / 16) / 4;  // 2304 blocks, 4 waves each
  const int nb2 = (BPIX / 16) / 4;  // 2304

  if (fused) {
    hipLaunchKernelGGL((kernelB1m<1, 0>), dim3(nb1), dim3(256), 0, stream,
                       h0, wm, scale, cat0);
    hipLaunchKernelGGL((kernelB1m<5, 1>), dim3(nb1), dim3(256), 0, stream,
                       h1, wm, scale, cat1);
    hipLaunchKernelGGL(kernelB2fused, dim3(nb2), dim3(256), 0, stream,
                       cat0, cat1, wb, out_b, out);
  } else {
    hipLaunchKernelGGL((kernelB1m<1, 0>), dim3(nb1), dim3(256), 0, stream,
                       h0, wm, scale, cat0);
    hipLaunchKernelGGL((kernelB2<0, false>), dim3(nb2), dim3(256), 0, stream,
                       cat0, wb, out_b, out);
    hipLaunchKernelGGL((kernelB1m<5, 1>), dim3(nb1), dim3(256), 0, stream,
                       h1, w1_1 ? wm : wm, scale, cat1);
    hipLaunchKernelGGL((kernelB2<1, true>), dim3(nb2), dim3(256), 0, stream,
                       cat1, wb, out_b, out);
  }
}

// Round 5
// 642.750 us; speedup vs baseline: 1.0252x; 1.0165x over previous
//
#include <hip/hip_runtime.h>
#include <hip/hip_bf16.h>
#include <cstddef>
#include <cstdint>

// Problem constants
#define BATCH 4
#define INC   256
#define HID   16
#define NL    9
#define HH    192
#define WW    192
#define PIX   (HH*WW)          // 36864
#define BPIX  (BATCH*PIX)      // 147456
#define OUTC  128
#define CATC  (NL*HID*2)       // 288
#define CATK  160              // per-branch K padded 144 -> 160 (5 x 32)

// cen_t plane layout: [b][y][kc=c/32][x][c%32]  (ushorts)
#define KCSTRIDE (WW*32)       // 6144 ushorts between kc chunks
#define ROWSTRIDE (8*WW*32)    // 49152 ushorts per (b,y) row

typedef __attribute__((ext_vector_type(8))) short bf16x8;
typedef __attribute__((ext_vector_type(4))) float f32x4;
typedef unsigned short ushort_t;

__device__ inline unsigned short f2bf(float f) {
  unsigned int u = __float_as_uint(f);
  u += 0x7FFF + ((u >> 16) & 1);   // round-to-nearest-even
  return (unsigned short)(u >> 16);
}
__device__ inline float bf2f(unsigned short s) {
  return __uint_as_float(((unsigned)s) << 16);
}
__device__ inline unsigned pack2(float a, float b) {
  return (unsigned)f2bf(a) | ((unsigned)f2bf(b) << 16);
}
__device__ inline bf16x8 cvt8(float4 a, float4 b) {
  union { bf16x8 v; unsigned u[4]; } r;
  r.u[0] = pack2(a.x, a.y); r.u[1] = pack2(a.z, a.w);
  r.u[2] = pack2(b.x, b.y); r.u[3] = pack2(b.z, b.w);
  return r.v;
}

// ---------------------------------------------------------------------------
// kernelP: cen (NCHW fp32) -> cen_t hi/lo planes [b][y][kc][x][32c] bf16
// ---------------------------------------------------------------------------
__global__ __launch_bounds__(256) void kernelP(const float* __restrict__ cen,
                                               ushort_t* __restrict__ th,
                                               ushort_t* __restrict__ tl) {
  __shared__ float t[256][17];
  const int b = blockIdx.z, y = blockIdx.y, x0 = blockIdx.x * 16;
  const int tid = threadIdx.x;
#pragma unroll
  for (int k = 0; k < 16; ++k) {
    int i = tid + k * 256; int c = i >> 4, xl = i & 15;
    t[c][xl] = cen[((size_t)(b * 256 + c)) * PIX + (size_t)y * WW + x0 + xl];
  }
  __syncthreads();
  const size_t rowbase = (size_t)(b * HH + y) * ROWSTRIDE;
  const int kcq = tid >> 5;        // 0..7  (channel chunk)
  const int c32 = tid & 31;        // channel within chunk
  const size_t obase = rowbase + (size_t)kcq * KCSTRIDE + c32;
#pragma unroll
  for (int xl = 0; xl < 16; ++xl) {
    float v = t[tid][xl];
    unsigned short hi = f2bf(v);
    const size_t a = obase + (size_t)(x0 + xl) * 32;
    th[a] = hi;
    tl[a] = f2bf(v - bf2f(hi));
  }
}

// ---------------------------------------------------------------------------
// wprepA: MFMA-frag-ready bf16 hi/lo weights for the two input convs.
// ---------------------------------------------------------------------------
__global__ __launch_bounds__(256) void wprepA(
    const float* __restrict__ w0, const float* __restrict__ w1,
    ushort_t* __restrict__ wA0hi, ushort_t* __restrict__ wA0lo,
    ushort_t* __restrict__ wA1hi, ushort_t* __restrict__ wA1lo) {
  int idx = blockIdx.x * 256 + threadIdx.x;
  if (idx < 36864) {
    int j = idx & 7, l = (idx >> 3) & 63, kc = (idx >> 9) & 7, s = idx >> 12;
    int d = l & 15, c = kc * 32 + (l >> 4) * 8 + j;
    float v = w1[(size_t)(d * 256 + c) * 9 + s];
    unsigned short hi = f2bf(v);
    wA1hi[idx] = hi; wA1lo[idx] = f2bf(v - bf2f(hi));
  }
  if (idx < 4096) {
    int j = idx & 7, l = (idx >> 3) & 63, kc = idx >> 9;
    int d = l & 15, c = kc * 32 + (l >> 4) * 8 + j;
    float v = w0[d * 256 + c];
    unsigned short hi = f2bf(v);
    wA0hi[idx] = hi; wA0lo[idx] = f2bf(v - bf2f(hi));
  }
}

// ---------------------------------------------------------------------------
// wprepB: out_w (fp32, [128][288]) -> wb (bf16, [branch][128][CATK]), K-padded
// ---------------------------------------------------------------------------
__global__ __launch_bounds__(256) void wprepB(const float* __restrict__ out_w,
                                              ushort_t* __restrict__ wb) {
  int idx = blockIdx.x * 256 + threadIdx.x;
  if (idx >= 2 * OUTC * CATK) return;
  int k = idx % CATK; int rest = idx / CATK;
  int o = rest % OUTC; int br = rest / OUTC;
  float v = (k < 144) ? out_w[o * CATC + br * 144 + k] : 0.f;
  wb[idx] = f2bf(v);
}

// ---------------------------------------------------------------------------
// wprepM: w1/w2/w3 (both branches) -> A-frag bf16 layout for kernelB1m.
// ---------------------------------------------------------------------------
__global__ __launch_bounds__(256) void wprepM(
    const float* __restrict__ w1_0, const float* __restrict__ w2_0,
    const float* __restrict__ w3_0, const float* __restrict__ w1_1,
    const float* __restrict__ w2_1, const float* __restrict__ w3_1,
    ushort_t* __restrict__ wm) {
  int idx = blockIdx.x * 256 + threadIdx.x;
  if (idx >= 2 * 27 * 512) return;
  int j = idx & 7;
  int lane = (idx >> 3) & 63;
  int blk = idx >> 9;               // br*27 + mat*9 + g
  int g = blk % 9, mat = (blk / 9) % 3, br = blk / 27;
  int d = lane & 15, k = (lane >> 4) * 8 + j;
  float v = 0.f;
  if (k < 16) {
    const float* w;
    if (br == 0) w = (mat == 0) ? w1_0 : (mat == 1) ? w2_0 : w3_0;
    else         w = (mat == 0) ? w1_1 : (mat == 1) ? w2_1 : w3_1;
    v = w[(g * 16 + d) * 16 + k];
    if (g < 8) v = -v;
  }
  wm[idx] = f2bf(v);
}

// ---------------------------------------------------------------------------
// kernelA_mfma: acc1 += 3x3 conv (9 taps), acc0 += 1x1 (center), hi/lo bf16.
// Per tap: batch all 16 data loads (8 kc x hi/lo) into registers BEFORE the
// MFMA block -> 16 loads in flight per tap instead of ~2 (the round-2
// bottleneck: VGPR=56, everything idle, latency-bound).
// Output h layout: NHWC [b][pix][16] fp32.
// ---------------------------------------------------------------------------
template <bool SAFE>
__device__ inline void a_tile(const ushort_t* __restrict__ th,
                              const ushort_t* __restrict__ tl,
                              const ushort_t* __restrict__ wA0hi,
                              const ushort_t* __restrict__ wA0lo,
                              const ushort_t* __restrict__ wA1hi,
                              const ushort_t* __restrict__ wA1lo,
                              int b, int y, int px, f32x4& acc0, f32x4& acc1) {
  const int lane = threadIdx.x & 63;
  const int quad = lane >> 4;
  const bf16x8 bz = {0, 0, 0, 0, 0, 0, 0, 0};
#pragma unroll
  for (int sy = 0; sy < 3; ++sy) {
    const int yy = y + sy - 1;
    const bool yok = SAFE || ((unsigned)yy < (unsigned)HH);
#pragma unroll
    for (int sx = 0; sx < 3; ++sx) {
      const int xx = px + sx - 1;
      const bool ok = SAFE || (yok && ((unsigned)xx < (unsigned)WW));
      const int cy = SAFE ? yy : (ok ? yy : 0);
      const int cx = SAFE ? xx : (ok ? xx : 0);
      const size_t base =
          (size_t)(b * HH + cy) * ROWSTRIDE + (size_t)cx * 32 + quad * 8;
      const int s = sy * 3 + sx;
      const ushort_t* wh = wA1hi + s * 4096 + lane * 8;
      const ushort_t* wl = wA1lo + s * 4096 + lane * 8;

      // ---- batched data loads: 16 outstanding ----
      bf16x8 bh[8], bl[8];
#pragma unroll
      for (int kc = 0; kc < 8; ++kc) {
        bh[kc] = *(const bf16x8*)(th + base + kc * KCSTRIDE);
        bl[kc] = *(const bf16x8*)(tl + base + kc * KCSTRIDE);
      }
      if (!SAFE && !ok) {
#pragma unroll
        for (int kc = 0; kc < 8; ++kc) { bh[kc] = bz; bl[kc] = bz; }
      }

      // ---- MFMA block ----
#pragma unroll
      for (int kc = 0; kc < 8; ++kc) {
        bf16x8 ahi = *(const bf16x8*)(wh + kc * 512);
        bf16x8 alo = *(const bf16x8*)(wl + kc * 512);
        acc1 = __builtin_amdgcn_mfma_f32_16x16x32_bf16(ahi, bh[kc], acc1, 0, 0, 0);
        acc1 = __builtin_amdgcn_mfma_f32_16x16x32_bf16(ahi, bl[kc], acc1, 0, 0, 0);
        acc1 = __builtin_amdgcn_mfma_f32_16x16x32_bf16(alo, bh[kc], acc1, 0, 0, 0);
        if (s == 4) {
          bf16x8 a0h = *(const bf16x8*)(wA0hi + kc * 512 + lane * 8);
          bf16x8 a0l = *(const bf16x8*)(wA0lo + kc * 512 + lane * 8);
          acc0 = __builtin_amdgcn_mfma_f32_16x16x32_bf16(a0h, bh[kc], acc0, 0, 0, 0);
          acc0 = __builtin_amdgcn_mfma_f32_16x16x32_bf16(a0h, bl[kc], acc0, 0, 0, 0);
          acc0 = __builtin_amdgcn_mfma_f32_16x16x32_bf16(a0l, bh[kc], acc0, 0, 0, 0);
        }
      }
    }
  }
}

// Grid: 1-D, 2304 blocks, natural order (round-2 post-mortem: XCD swizzle
// ADDED 95 MB of fetch via per-XCD L2 thrash — reverted).
__global__ __launch_bounds__(256) void kernelA_mfma(
    const ushort_t* __restrict__ th, const ushort_t* __restrict__ tl,
    const ushort_t* __restrict__ wA0hi, const ushort_t* __restrict__ wA0lo,
    const ushort_t* __restrict__ wA1hi, const ushort_t* __restrict__ wA1lo,
    const float* __restrict__ b0, const float* __restrict__ b1,
    float* __restrict__ h0, float* __restrict__ h1) {
  const int lt = blockIdx.x;
  const int xb = lt % 3;
  const int y  = (lt / 3) % HH;
  const int b  = lt / (3 * HH);

  const int lane = threadIdx.x & 63, wave = threadIdx.x >> 6;
  const int n = lane & 15, quad = lane >> 4;
  const int wpx0 = xb * 64 + wave * 16;
  const int px = wpx0 + n;
  f32x4 acc0 = {0.f, 0.f, 0.f, 0.f}, acc1 = {0.f, 0.f, 0.f, 0.f};

  const bool safe = (y >= 1) && (y <= HH - 2) && (wpx0 >= 1) && (wpx0 + 16 <= WW - 1);
  if (safe)
    a_tile<true>(th, tl, wA0hi, wA0lo, wA1hi, wA1lo, b, y, px, acc0, acc1);
  else
    a_tile<false>(th, tl, wA0hi, wA0lo, wA1hi, wA1lo, b, y, px, acc0, acc1);

  // NHWC store: lane holds d = quad*4 + i for pixel px.
  const size_t pb = ((size_t)b * PIX + (size_t)y * WW + px) * 16 + quad * 4;
  float4 r0, r1;
  r0.x = acc0[0] + b0[quad * 4 + 0]; r0.y = acc0[1] + b0[quad * 4 + 1];
  r0.z = acc0[2] + b0[quad * 4 + 2]; r0.w = acc0[3] + b0[quad * 4 + 3];
  r1.x = acc1[0] + b1[quad * 4 + 0]; r1.y = acc1[1] + b1[quad * 4 + 1];
  r1.z = acc1[2] + b1[quad * 4 + 2]; r1.w = acc1[3] + b1[quad * 4 + 3];
  *(float4*)(h0 + pb) = r0;
  *(float4*)(h1 + pb) = r1;
}

// ---------------------------------------------------------------------------
// kernelA_f32: fallback when ws too small for cen_t planes. NHWC output.
// ---------------------------------------------------------------------------
__global__ __launch_bounds__(256) void kernelA_f32(
    const float* __restrict__ cen, const float* __restrict__ w0,
    const float* __restrict__ b0,  const float* __restrict__ w1,
    const float* __restrict__ b1,  float* __restrict__ h0,
    float* __restrict__ h1) {
  __shared__ float lds[16 * 18 * 18];
  const int lx = threadIdx.x, ly = threadIdx.y;
  const int tid = ly * 16 + lx;
  const int x0 = blockIdx.x * 16, y0 = blockIdx.y * 16, b = blockIdx.z;

  float acc0[16], acc1[16];
#pragma unroll
  for (int d = 0; d < 16; ++d) { acc0[d] = 0.f; acc1[d] = 0.f; }

  for (int cb = 0; cb < INC; cb += 16) {
    __syncthreads();
    for (int i = tid; i < 16 * 18 * 18; i += 256) {
      int c = i / 324; int rem = i - c * 324;
      int yy = rem / 18; int xx = rem - yy * 18;
      int gy = y0 + yy - 1, gx = x0 + xx - 1;
      float v = 0.f;
      if (gy >= 0 && gy < HH && gx >= 0 && gx < WW)
        v = cen[(((size_t)b * INC + cb + c) * HH + gy) * WW + gx];
      lds[i] = v;
    }
    __syncthreads();
    for (int c = 0; c < 16; ++c) {
      float v[9];
#pragma unroll
      for (int r = 0; r < 9; ++r) {
        const int dy = r / 3, dx = r - (r / 3) * 3;
        v[r] = lds[(c * 18 + ly + dy) * 18 + lx + dx];
      }
      const int cc = cb + c;
#pragma unroll
      for (int d = 0; d < 16; ++d)
        acc0[d] = fmaf(w0[d * INC + cc], v[4], acc0[d]);
#pragma unroll
      for (int d = 0; d < 16; ++d) {
        float a = acc1[d];
#pragma unroll
        for (int r = 0; r < 9; ++r)
          a = fmaf(w1[(d * INC + cc) * 9 + r], v[r], a);
        acc1[d] = a;
      }
    }
  }
  const int y = y0 + ly, x = x0 + lx;
  const size_t base = ((size_t)b * PIX + (size_t)y * WW + x) * 16;
#pragma unroll
  for (int k = 0; k < 4; ++k) {
    float4 r0, r1;
    r0.x = acc0[4 * k + 0] + b0[4 * k + 0]; r0.y = acc0[4 * k + 1] + b0[4 * k + 1];
    r0.z = acc0[4 * k + 2] + b0[4 * k + 2]; r0.w = acc0[4 * k + 3] + b0[4 * k + 3];
    r1.x = acc1[4 * k + 0] + b1[4 * k + 0]; r1.y = acc1[4 * k + 1] + b1[4 * k + 1];
    r1.z = acc1[4 * k + 2] + b1[4 * k + 2]; r1.w = acc1[4 * k + 3] + b1[4 * k + 3];
    *(float4*)(h0 + base + 4 * k) = r0;
    *(float4*)(h1 + base + 4 * k) = r1;
  }
}

// ---------------------------------------------------------------------------
// kernelB1m: wave-cooperative attention. Wave = 16 pixels of one row.
// ---------------------------------------------------------------------------
template <int SHIFT, int BRANCH>
__global__ __launch_bounds__(256) void kernelB1m(
    const float* __restrict__ h,      // [b][pix][16] fp32
    const ushort_t* __restrict__ wm,  // [br][3][9][512] bf16 A-frags
    const float* __restrict__ scale, ushort_t* __restrict__ cat) {
  const int lane = threadIdx.x & 63;
  const int gw = blockIdx.x * 4 + (threadIdx.x >> 6);
  const int bpix0 = gw * 16;
  const int b = bpix0 / PIX;
  const int rem = bpix0 - b * PIX;
  const int y = rem / WW, x0 = rem - y * WW;
  const int n = lane & 15, quad = lane >> 4;
  const float sc = scale[BRANCH];
  const float* __restrict__ hb = h + (size_t)b * PIX * 16;
  const ushort_t* __restrict__ wmb = wm + (size_t)BRANCH * 27 * 512;

  constexpr int DY[9] = {-1, -1, -1, 0, 1, 1, 1, 0, 0};
  constexpr int DX[9] = {-1, 0, 1, 1, 1, 0, -1, -1, 0};

  // B-frags: lane provides B[k = quad*8+j][pixel n]; k>=16 must be zero.
  bf16x8 xf[9];
#pragma unroll
  for (int g = 0; g < 9; ++g) {
    bf16x8 v = {0, 0, 0, 0, 0, 0, 0, 0};
    const int yy = y + DY[g] * SHIFT;
    const int xx = x0 + n + DX[g] * SHIFT;
    if (quad < 2 && (unsigned)yy < (unsigned)HH && (unsigned)xx < (unsigned)WW) {
      const float4* p = (const float4*)(hb + ((size_t)yy * WW + xx) * 16 + quad * 8);
      v = cvt8(p[0], p[1]);
    }
    xf[g] = v;
  }

  const f32x4 zero4 = {0.f, 0.f, 0.f, 0.f};
  f32x4 o1[9], o3[9];
#pragma unroll
  for (int g = 0; g < 9; ++g) {
    const bf16x8 a1 = *(const bf16x8*)(wmb + (0 * 9 + g) * 512 + lane * 8);
    o1[g] = __builtin_amdgcn_mfma_f32_16x16x32_bf16(a1, xf[g], zero4, 0, 0, 0);
  }
#pragma unroll
  for (int g = 0; g < 9; ++g) {
    const bf16x8 a3 = *(const bf16x8*)(wmb + (2 * 9 + g) * 512 + lane * 8);
    o3[g] = __builtin_amdgcn_mfma_f32_16x16x32_bf16(a3, xf[g], zero4, 0, 0, 0);
  }

  ushort_t* __restrict__ crow = cat + (size_t)(bpix0 + n) * CATK;

#pragma unroll
  for (int p = 0; p < 9; ++p) {
    const bf16x8 a2 = *(const bf16x8*)(wmb + (1 * 9 + p) * 512 + lane * 8);
    const f32x4 o2p = __builtin_amdgcn_mfma_f32_16x16x32_bf16(a2, xf[p], zero4, 0, 0, 0);
    float e[9]; float m = -1e30f;
#pragma unroll
    for (int q = 0; q < 9; ++q) {
      float t = (o2p[0] * o1[q][0] + o2p[1] * o1[q][1]) +
                (o2p[2] * o1[q][2] + o2p[3] * o1[q][3]);
      t += __shfl_xor(t, 16);
      t += __shfl_xor(t, 32);
      e[q] = sc * t;
      m = fmaxf(m, e[q]);
    }
    float s = 0.f;
#pragma unroll
    for (int q = 0; q < 9; ++q) { e[q] = __expf(e[q] - m); s += e[q]; }
    const float inv = 1.0f / s;
    f32x4 ov = zero4;
#pragma unroll
    for (int q = 0; q < 9; ++q) {
      const float a = e[q] * inv;
      ov[0] = fmaf(a, o3[q][0], ov[0]);
      ov[1] = fmaf(a, o3[q][1], ov[1]);
      ov[2] = fmaf(a, o3[q][2], ov[2]);
      ov[3] = fmaf(a, o3[q][3], ov[3]);
    }
    uint2 w; w.x = pack2(ov[0], ov[1]); w.y = pack2(ov[2], ov[3]);
    *(uint2*)(crow + p * 16 + quad * 4) = w;
  }
  // zero K-pad [144,160): quads 0/1 write 8 ushorts each
  if (quad < 2)
    *(uint4*)(crow + 144 + quad * 8) = make_uint4(0, 0, 0, 0);
}

// ---------------------------------------------------------------------------
// Kernel B2 split and fused variants (final 1x1 conv as bf16 MFMA GEMM).
// ---------------------------------------------------------------------------
template <int BRANCH, bool ACCUM>
__global__ __launch_bounds__(256) void kernelB2(
    const ushort_t* __restrict__ cat, const ushort_t* __restrict__ wb,
    const float* __restrict__ out_b, float* __restrict__ out) {
  const int wave = threadIdx.x >> 6;
  const int lane = threadIdx.x & 63;
  const int tile = blockIdx.x * 4 + wave;
  const int bpix0 = tile * 16;
  const int n = lane & 15, quad = lane >> 4;

  const bf16x8* __restrict__ bp =
      (const bf16x8*)(cat + (size_t)(bpix0 + n) * CATK + quad * 8);
  const ushort_t* __restrict__ wrow0 =
      wb + ((size_t)BRANCH * OUTC + n) * CATK + quad * 8;

  f32x4 acc[8];
#pragma unroll
  for (int mt = 0; mt < 8; ++mt) acc[mt] = (f32x4){0.f, 0.f, 0.f, 0.f};

#pragma unroll
  for (int kc = 0; kc < 5; ++kc) {
    const bf16x8 bfrag = bp[kc * 4];
#pragma unroll
    for (int mt = 0; mt < 8; ++mt) {
      const bf16x8 afrag =
          *(const bf16x8*)(wrow0 + (size_t)mt * 16 * CATK + kc * 32);
      acc[mt] = __builtin_amdgcn_mfma_f32_16x16x32_bf16(afrag, bfrag, acc[mt], 0, 0, 0);
    }
  }

  const int b = bpix0 / PIX;
  const int pin = bpix0 - b * PIX + n;
#pragma unroll
  for (int mt = 0; mt < 8; ++mt) {
#pragma unroll
    for (int i = 0; i < 4; ++i) {
      const int o = mt * 16 + quad * 4 + i;
      const size_t addr = ((size_t)(b * OUTC + o)) * PIX + pin;
      float r = acc[mt][i];
      if (ACCUM) r += out[addr]; else r += out_b[o];
      out[addr] = r;
    }
  }
}

__global__ __launch_bounds__(256) void kernelB2fused(
    const ushort_t* __restrict__ cat0, const ushort_t* __restrict__ cat1,
    const ushort_t* __restrict__ wb, const float* __restrict__ out_b,
    float* __restrict__ out) {
  const int wave = threadIdx.x >> 6;
  const int lane = threadIdx.x & 63;
  const int tile = blockIdx.x * 4 + wave;
  const int bpix0 = tile * 16;
  const int n = lane & 15, quad = lane >> 4;

  f32x4 acc[8];
#pragma unroll
  for (int mt = 0; mt < 8; ++mt) acc[mt] = (f32x4){0.f, 0.f, 0.f, 0.f};

#pragma unroll
  for (int br = 0; br < 2; ++br) {
    const ushort_t* cp = br ? cat1 : cat0;
    const bf16x8* __restrict__ bp =
        (const bf16x8*)(cp + (size_t)(bpix0 + n) * CATK + quad * 8);
    const ushort_t* __restrict__ wrow0 =
        wb + ((size_t)br * OUTC + n) * CATK + quad * 8;
#pragma unroll
    for (int kc = 0; kc < 5; ++kc) {
      const bf16x8 bfrag = bp[kc * 4];
#pragma unroll
      for (int mt = 0; mt < 8; ++mt) {
        const bf16x8 afrag =
            *(const bf16x8*)(wrow0 + (size_t)mt * 16 * CATK + kc * 32);
        acc[mt] = __builtin_amdgcn_mfma_f32_16x16x32_bf16(afrag, bfrag, acc[mt], 0, 0, 0);
      }
    }
  }

  const int b = bpix0 / PIX;
  const int pin = bpix0 - b * PIX + n;
#pragma unroll
  for (int mt = 0; mt < 8; ++mt) {
#pragma unroll
    for (int i = 0; i < 4; ++i) {
      const int o = mt * 16 + quad * 4 + i;
      const size_t addr = ((size_t)(b * OUTC + o)) * PIX + pin;
      out[addr] = acc[mt][i] + out_b[o];
    }
  }
}

// ---------------------------------------------------------------------------
extern "C" void kernel_launch(void* const* d_in, const int* in_sizes, int n_in,
                              void* d_out, int out_size, void* d_ws, size_t ws_size,
                              hipStream_t stream) {
  const float* cen   = (const float*)d_in[0];
  const float* in_w0 = (const float*)d_in[1];
  const float* in_b0 = (const float*)d_in[2];
  const float* in_w1 = (const float*)d_in[3];
  const float* in_b1 = (const float*)d_in[4];
  const float* w1_0  = (const float*)d_in[5];
  const float* w2_0  = (const float*)d_in[6];
  const float* w3_0  = (const float*)d_in[7];
  const float* w1_1  = (const float*)d_in[8];
  const float* w2_1  = (const float*)d_in[9];
  const float* w3_1  = (const float*)d_in[10];
  const float* scale = (const float*)d_in[11];
  const float* out_w = (const float*)d_in[12];
  const float* out_b = (const float*)d_in[13];
  float* out = (float*)d_out;

  // ---- ws layout ----
  const size_t H_ELEMS = (size_t)BATCH * HID * PIX;        // 2359296 floats
  const size_t PLANE_E = (size_t)BPIX * 256;               // cen_t plane, ushorts
  const size_t CAT_E   = (size_t)BPIX * CATK;              // cat, ushorts

  float* h0 = (float*)d_ws;
  float* h1 = h0 + H_ELEMS;
  ushort_t* wsm = (ushort_t*)(h1 + H_ELEMS);
  ushort_t* wA0hi = wsm;                 // 4096
  ushort_t* wA0lo = wsm + 4096;          // 4096
  ushort_t* wA1hi = wsm + 8192;          // 36864
  ushort_t* wA1lo = wsm + 45056;         // 36864
  ushort_t* wb    = wsm + 81920;         // 40960
  ushort_t* wm    = wsm + 122880;        // 27648
  ushort_t* big   = wsm + 150528;

  const size_t base_bytes = 2 * H_ELEMS * 4 + 150528 * 2;
  const size_t fast_need       = base_bytes + 2 * PLANE_E * 2;   // ~170 MB
  const size_t slow_fused_need = base_bytes + 2 * CAT_E * 2;     // ~114 MB
  const bool fast  = ws_size >= fast_need;
  const bool fused = fast || ws_size >= slow_fused_need;

  ushort_t* cat0 = big;                         // fast: aliases cen_t (stream-ordered)
  ushort_t* cat1 = fused ? (big + CAT_E) : big;

  // ---- weight preps ----
  hipLaunchKernelGGL(wprepB, dim3((2 * OUTC * CATK + 255) / 256), dim3(256), 0,
                     stream, out_w, wb);
  hipLaunchKernelGGL(wprepM, dim3((2 * 27 * 512 + 255) / 256), dim3(256), 0,
                     stream, w1_0, w2_0, w3_0, w1_1, w2_1, w3_1, wm);

  // ---- input convs ----
  if (fast) {
    ushort_t* th = big;
    ushort_t* tl = big + PLANE_E;
    hipLaunchKernelGGL(wprepA, dim3(144), dim3(256), 0, stream,
                       in_w0, in_w1, wA0hi, wA0lo, wA1hi, wA1lo);
    hipLaunchKernelGGL(kernelP, dim3(WW / 16, HH, BATCH), dim3(256), 0, stream,
                       cen, th, tl);
    hipLaunchKernelGGL(kernelA_mfma, dim3(3 * HH * BATCH), dim3(256), 0, stream,
                       th, tl, wA0hi, wA0lo, wA1hi, wA1lo, in_b0, in_b1, h0, h1);
  } else {
    hipLaunchKernelGGL(kernelA_f32, dim3(WW / 16, HH / 16, BATCH), dim3(16, 16), 0,
                       stream, cen, in_w0, in_b0, in_w1, in_b1, h0, h1);
  }

  const int nb1 = (BPIX / 16) / 4;  // 2304 blocks, 4 waves each
  const int nb2 = (BPIX / 16) / 4;  // 2304

  if (fused) {
    hipLaunchKernelGGL((kernelB1m<1, 0>), dim3(nb1), dim3(256), 0, stream,
                       h0, wm, scale, cat0);
    hipLaunchKernelGGL((kernelB1m<5, 1>), dim3(nb1), dim3(256), 0, stream,
                       h1, wm, scale, cat1);
    hipLaunchKernelGGL(kernelB2fused, dim3(nb2), dim3(256), 0, stream,
                       cat0, cat1, wb, out_b, out);
  } else {
    hipLaunchKernelGGL((kernelB1m<1, 0>), dim3(nb1), dim3(256), 0, stream,
                       h0, wm, scale, cat0);
    hipLaunchKernelGGL((kernelB2<0, false>), dim3(nb2), dim3(256), 0, stream,
                       cat0, wb, out_b, out);
    hipLaunchKernelGGL((kernelB1m<5, 1>), dim3(nb1), dim3(256), 0, stream,
                       h1, w1_1 ? wm : wm, scale, cat1);
    hipLaunchKernelGGL((kernelB2<1, true>), dim3(nb2), dim3(256), 0, stream,
                       cat1, wb, out_b, out);
  }
}